// Round 2
// baseline (437.288 us; speedup 1.0000x reference)
//
#include <hip/hip_runtime.h>
#include <math.h>

#define B_ 8
#define T_ 1024
#define V_ 10000
#define NV4 (V_ / 4)   // 2500 float4 per frame (V_ % 4 == 0, rows 16B-aligned: 40000 % 16 == 0)
#define BLANK_ 0

// ---------------------------------------------------------------------------
// Kernel 1: per-frame online softmax reduction.
// One block per (b,t) frame. Computes argmax(logits) and
// maxlogp = -log(sum exp(l - max)) in a single pass over V=10000.
// Also zeroes this frame's tokens output slot (d_out is poisoned 0xAA).
// ---------------------------------------------------------------------------
__global__ __launch_bounds__(256) void frame_reduce_kernel(
    const float* __restrict__ logits,
    int*   __restrict__ preds,     // [B*T] workspace
    float* __restrict__ mlp,       // [B*T] workspace
    float* __restrict__ tokens)    // [B*T] output (zeroed here; fp32 view!)
{
    const int frame = blockIdx.x;
    const int tid   = threadIdx.x;
    const float4* row = (const float4*)(logits + (size_t)frame * V_);

    float m = -INFINITY;
    float s = 0.0f;
    int   idx = 0;

    for (int i = tid; i < NV4; i += 256) {
        float4 v4 = row[i];
        float vv[4] = {v4.x, v4.y, v4.z, v4.w};
#pragma unroll
        for (int c = 0; c < 4; ++c) {
            float v = vv[c];
            float d = v - m;                  // d > 0 means new max
            float e = __expf(-fabsf(d));      // exp(m-v) if new max, exp(v-m) otherwise
            if (d > 0.0f) {                   // strict > keeps FIRST occurrence (jnp.argmax)
                s = s * e + 1.0f;             // rescale old sum, add exp(0)=1 for v itself
                m = v;
                idx = i * 4 + c;
            } else {
                s += e;
            }
        }
    }

    // wave-level reduce (64 lanes)
#pragma unroll
    for (int off = 32; off > 0; off >>= 1) {
        float m2 = __shfl_down(m, off);
        float s2 = __shfl_down(s, off);
        int   i2 = __shfl_down(idx, off);
        if (m2 > m || (m2 == m && i2 < idx)) {
            s = s2 + s * __expf(m - m2);
            m = m2;
            idx = i2;
        } else {
            s = s + s2 * __expf(m2 - m);
        }
    }

    // cross-wave reduce (4 waves)
    __shared__ float sm[4], ss[4];
    __shared__ int   si[4];
    const int wave = tid >> 6;
    if ((tid & 63) == 0) { sm[wave] = m; ss[wave] = s; si[wave] = idx; }
    __syncthreads();
    if (tid == 0) {
#pragma unroll
        for (int w = 1; w < 4; ++w) {
            float m2 = sm[w], s2 = ss[w];
            int   i2 = si[w];
            if (m2 > m || (m2 == m && i2 < idx)) {
                s = s2 + s * __expf(m - m2);
                m = m2;
                idx = i2;
            } else {
                s = s + s2 * __expf(m2 - m);
            }
        }
        preds[frame]  = idx;
        mlp[frame]    = -__logf(s);   // maxlogp = m - logsumexp = -log(sum exp(l-m))
        tokens[frame] = 0.0f;         // zero-init output; kernel 2 scatters over this
    }
}

// ---------------------------------------------------------------------------
// Kernel 2: CTC collapse. One wave (64 threads) per batch row.
// keep[t] = (t < len) && (pred != BLANK) && (pred != pred[t-1]); left-pack.
// All outputs stored as float32 (harness reads flat buffer as fp32).
// ---------------------------------------------------------------------------
__global__ __launch_bounds__(64) void collapse_kernel(
    const int*   __restrict__ preds,    // [B*T]
    const float* __restrict__ mlp,      // [B*T]
    const int*   __restrict__ lengths,  // [B]
    float* __restrict__ tokens,         // [B*T] (already zeroed by kernel 1)
    float* __restrict__ out_len,        // [B]
    float* __restrict__ scores)         // [B]
{
    const int b    = blockIdx.x;
    const int lane = threadIdx.x;
    const int len  = lengths[b];
    const int* prow = preds + b * T_;
    const float* srow = mlp + b * T_;
    float* trow = tokens + b * T_;

    int   base = 0;
    float score_acc = 0.0f;

#pragma unroll 1
    for (int chunk = 0; chunk < T_ / 64; ++chunk) {
        const int t = chunk * 64 + lane;
        const int p    = prow[t];
        const int prev = (t == 0) ? BLANK_ : prow[t - 1];
        const bool keep = (t < len) && (p != BLANK_) && (p != prev);
        const unsigned long long mask = __ballot(keep);
        const int pos = base + __popcll(mask & ((1ull << lane) - 1ull));
        if (keep) {
            trow[pos] = (float)p;       // token ids < 10000: exact in fp32
            score_acc += srow[t];
        }
        base += __popcll(mask);
    }

    // wave reduce the score
#pragma unroll
    for (int off = 32; off > 0; off >>= 1)
        score_acc += __shfl_down(score_acc, off);

    if (lane == 0) {
        out_len[b] = (float)base;       // <= 1024: exact in fp32
        scores[b]  = score_acc;
    }
}

extern "C" void kernel_launch(void* const* d_in, const int* in_sizes, int n_in,
                              void* d_out, int out_size, void* d_ws, size_t ws_size,
                              hipStream_t stream) {
    const float* logits  = (const float*)d_in[0];
    const int*   lengths = (const int*)d_in[1];

    // Output layout (fp32 view): tokens [B*T] | out_len [B] | scores [B]
    float* out_f  = (float*)d_out;
    float* tokens = out_f;
    float* outlen = out_f + B_ * T_;
    float* scores = out_f + B_ * T_ + B_;

    // Workspace: preds [B*T] int32, mlp [B*T] float32 (64 KB total)
    int*   preds = (int*)d_ws;
    float* mlp   = (float*)((char*)d_ws + (size_t)B_ * T_ * sizeof(int));

    frame_reduce_kernel<<<B_ * T_, 256, 0, stream>>>(logits, preds, mlp, tokens);
    collapse_kernel<<<B_, 64, 0, stream>>>(preds, mlp, lengths, tokens, outlen, scores);
}

// Round 4
// 403.264 us; speedup vs baseline: 1.0844x; 1.0844x over previous
//
#include <hip/hip_runtime.h>
#include <math.h>

#define B_ 8
#define T_ 1024
#define V_ 10000
#define NV4 2500          // float4 per frame row (40000 B, 16B-aligned)
#define BLANK_ 0
#define LOG2E 1.44269504088896340736f
#define LN2   0.69314718055994530942f

typedef float vf4 __attribute__((ext_vector_type(4)));  // native clang vector: OK for nontemporal builtins

#if __has_builtin(__builtin_amdgcn_exp2f)
#define EXP2F(x) __builtin_amdgcn_exp2f(x)
#else
#define EXP2F(x) exp2f(x)
#endif
#if __has_builtin(__builtin_amdgcn_logf)
#define LOG2F(x) __builtin_amdgcn_logf(x)
#else
#define LOG2F(x) log2f(x)
#endif

// ---------------------------------------------------------------------------
// Kernel 1: per-frame argmax + logsumexp, register-resident.
// One block per (b,t) frame. Each thread loads its 10 float4 chunks up front
// (10 outstanding nontemporal dwordx4 loads), then computes max/argmax and
// sum exp2 from registers — no load-compute serial chain, no branches.
// ---------------------------------------------------------------------------
__global__ __launch_bounds__(256) void frame_reduce_kernel(
    const float* __restrict__ logits,
    int*   __restrict__ preds,     // [B*T] workspace
    float* __restrict__ mlp,       // [B*T] workspace
    float* __restrict__ tokens)    // [B*T] output (zeroed here; fp32 view)
{
    const int frame = blockIdx.x;
    const int tid   = threadIdx.x;
    const vf4* row = (const vf4*)(logits + (size_t)frame * V_);

    // ---- stage all data into registers (loads issue back-to-back) ----
    vf4 r[10];
#pragma unroll
    for (int k = 0; k < 9; ++k)
        r[k] = __builtin_nontemporal_load(&row[tid + k * 256]);
    r[9] = (vf4){-INFINITY, -INFINITY, -INFINITY, -INFINITY};
    if (tid + 2304 < NV4)                      // threads 0..195 have a 10th chunk
        r[9] = __builtin_nontemporal_load(&row[tid + 2304]);

    // ---- pass 1: max + first-occurrence argmax (4 parallel chains) ----
    float m0 = -INFINITY, m1 = -INFINITY, m2 = -INFINITY, m3 = -INFINITY;
    int   i0 = 0x7fffffff, i1 = 0x7fffffff, i2 = 0x7fffffff, i3 = 0x7fffffff;
#pragma unroll
    for (int k = 0; k < 10; ++k) {
        const int gi = (tid + k * 256) * 4;    // ascending in k per chain
        if (r[k].x > m0) { m0 = r[k].x; i0 = gi + 0; }
        if (r[k].y > m1) { m1 = r[k].y; i1 = gi + 1; }
        if (r[k].z > m2) { m2 = r[k].z; i2 = gi + 2; }
        if (r[k].w > m3) { m3 = r[k].w; i3 = gi + 3; }
    }
    float m = m0;
    int   idx = i0;
    if (m1 > m || (m1 == m && i1 < idx)) { m = m1; idx = i1; }
    if (m2 > m || (m2 == m && i2 < idx)) { m = m2; idx = i2; }
    if (m3 > m || (m3 == m && i3 < idx)) { m = m3; idx = i3; }

    // ---- pass 2: s = sum exp(v - m), in exp2 domain, 4 accumulators ----
    const float mK = m * LOG2E;
    float s0 = 0.0f, s1 = 0.0f, s2 = 0.0f, s3 = 0.0f;
#pragma unroll
    for (int k = 0; k < 10; ++k) {
        s0 += EXP2F(__builtin_fmaf(r[k].x, LOG2E, -mK));
        s1 += EXP2F(__builtin_fmaf(r[k].y, LOG2E, -mK));
        s2 += EXP2F(__builtin_fmaf(r[k].z, LOG2E, -mK));
        s3 += EXP2F(__builtin_fmaf(r[k].w, LOG2E, -mK));
    }
    float s = (s0 + s1) + (s2 + s3);

    // ---- wave-level reduce (64 lanes) ----
#pragma unroll
    for (int off = 32; off > 0; off >>= 1) {
        float mo = __shfl_down(m, off);
        float so = __shfl_down(s, off);
        int   io = __shfl_down(idx, off);
        if (mo > m || (mo == m && io < idx)) {
            s = so + s * EXP2F((m - mo) * LOG2E);
            m = mo; idx = io;
        } else {
            s = s + so * EXP2F((mo - m) * LOG2E);
        }
    }

    // ---- cross-wave reduce (4 waves) ----
    __shared__ float sm[4], ss[4];
    __shared__ int   si[4];
    const int wave = tid >> 6;
    if ((tid & 63) == 0) { sm[wave] = m; ss[wave] = s; si[wave] = idx; }
    __syncthreads();
    if (tid == 0) {
#pragma unroll
        for (int w = 1; w < 4; ++w) {
            float mo = sm[w], so = ss[w];
            int   io = si[w];
            if (mo > m || (mo == m && io < idx)) {
                s = so + s * EXP2F((m - mo) * LOG2E);
                m = mo; idx = io;
            } else {
                s = s + so * EXP2F((mo - m) * LOG2E);
            }
        }
        preds[frame]  = idx;
        mlp[frame]    = -LOG2F(s) * LN2;   // maxlogp = -ln(sum exp(l-m))
        tokens[frame] = 0.0f;              // zero-init output; kernel 2 scatters
    }
}

// ---------------------------------------------------------------------------
// Kernel 2: CTC collapse. One wave per batch row; all 16 chunks prefetched
// into registers, prev via shuffle (no second load stream).
// Outputs stored as float32 (harness reads the flat buffer as fp32).
// ---------------------------------------------------------------------------
__global__ __launch_bounds__(64) void collapse_kernel(
    const int*   __restrict__ preds,    // [B*T]
    const float* __restrict__ mlp,      // [B*T]
    const int*   __restrict__ lengths,  // [B]
    float* __restrict__ tokens,         // [B*T] (zeroed by kernel 1)
    float* __restrict__ out_len,        // [B]
    float* __restrict__ scores)         // [B]
{
    const int b    = blockIdx.x;
    const int lane = threadIdx.x;
    const int len  = lengths[b];
    const int*   prow = preds + b * T_;
    const float* srow = mlp   + b * T_;
    float* trow = tokens + b * T_;

    int   p_r[16];
    float s_r[16];
#pragma unroll
    for (int c = 0; c < 16; ++c) {
        p_r[c] = prow[c * 64 + lane];
        s_r[c] = srow[c * 64 + lane];
    }

    int   base  = 0;
    int   carry = BLANK_;
    float acc   = 0.0f;
#pragma unroll
    for (int c = 0; c < 16; ++c) {
        const int t = c * 64 + lane;
        const int p = p_r[c];
        int prev = __shfl_up(p, 1);
        if (lane == 0) prev = carry;
        carry = __shfl(p, 63);
        const bool keep = (t < len) && (p != BLANK_) && (p != prev);
        const unsigned long long mask = __ballot(keep);
        const int pos = base + __popcll(mask & ((1ull << lane) - 1ull));
        if (keep) {
            trow[pos] = (float)p;       // token ids < 10000: exact in fp32
            acc += s_r[c];
        }
        base += __popcll(mask);
    }

#pragma unroll
    for (int off = 32; off > 0; off >>= 1)
        acc += __shfl_down(acc, off);

    if (lane == 0) {
        out_len[b] = (float)base;       // <= 1024: exact in fp32
        scores[b]  = acc;
    }
}

extern "C" void kernel_launch(void* const* d_in, const int* in_sizes, int n_in,
                              void* d_out, int out_size, void* d_ws, size_t ws_size,
                              hipStream_t stream) {
    const float* logits  = (const float*)d_in[0];
    const int*   lengths = (const int*)d_in[1];

    // Output layout (fp32 view): tokens [B*T] | out_len [B] | scores [B]
    float* out_f  = (float*)d_out;
    float* tokens = out_f;
    float* outlen = out_f + B_ * T_;
    float* scores = out_f + B_ * T_ + B_;

    // Workspace: preds [B*T] int32, mlp [B*T] float32 (64 KB total)
    int*   preds = (int*)d_ws;
    float* mlpws = (float*)((char*)d_ws + (size_t)B_ * T_ * sizeof(int));

    frame_reduce_kernel<<<B_ * T_, 256, 0, stream>>>(logits, preds, mlpws, tokens);
    collapse_kernel<<<B_, 64, 0, stream>>>(preds, mlpws, lengths, tokens, outlen, scores);
}

// Round 5
// 386.278 us; speedup vs baseline: 1.1321x; 1.0440x over previous
//
#include <hip/hip_runtime.h>
#include <math.h>

#define B_ 8
#define T_ 1024
#define V_ 10000
#define NV4 2500          // float4 per frame row (40000 B, 16B-aligned)
#define BLANK_ 0
#define LOG2E 1.44269504088896340736f
#define LN2   0.69314718055994530942f

typedef float vf4 __attribute__((ext_vector_type(4)));  // native clang vector: OK for nontemporal builtins

#if __has_builtin(__builtin_amdgcn_exp2f)
#define EXP2F(x) __builtin_amdgcn_exp2f(x)
#else
#define EXP2F(x) exp2f(x)
#endif
#if __has_builtin(__builtin_amdgcn_logf)
#define LOG2F(x) __builtin_amdgcn_logf(x)
#else
#define LOG2F(x) log2f(x)
#endif

// ---------------------------------------------------------------------------
// Kernel 1: per-frame argmax + logsumexp, register-resident, with validity
// early-exit. One block per (b,t) frame. Frames with t >= lengths[b] are
// never consumed by the collapse (keep==false there, and `prev` of a valid
// frame always refers to a valid frame), so those blocks skip the 40 KB row
// read entirely — on average halving HBM traffic (lengths ~ U[0,T)).
// Valid blocks: each thread stages its 10 float4 chunks up front (10
// outstanding nontemporal dwordx4), then branchless max/argmax + sum-exp2
// from registers.
// ---------------------------------------------------------------------------
__global__ __launch_bounds__(256) void frame_reduce_kernel(
    const float* __restrict__ logits,
    const int*   __restrict__ lengths,  // [B]
    int*   __restrict__ preds,     // [B*T] workspace (garbage for invalid frames)
    float* __restrict__ mlp,       // [B*T] workspace (garbage for invalid frames)
    float* __restrict__ tokens)    // [B*T] output (zeroed here; fp32 view)
{
    const int frame = blockIdx.x;
    const int tid   = threadIdx.x;
    const int b     = frame >> 10;       // frame / T_
    const int t     = frame & (T_ - 1);  // frame % T_

    if (t >= lengths[b]) {               // wave-uniform: scalar branch
        if (tid == 0) tokens[frame] = 0.0f;   // still must zero-init output
        return;
    }

    const vf4* row = (const vf4*)(logits + (size_t)frame * V_);

    // ---- stage all data into registers (loads issue back-to-back) ----
    vf4 r[10];
#pragma unroll
    for (int k = 0; k < 9; ++k)
        r[k] = __builtin_nontemporal_load(&row[tid + k * 256]);
    r[9] = (vf4){-INFINITY, -INFINITY, -INFINITY, -INFINITY};
    if (tid + 2304 < NV4)                      // threads 0..195 have a 10th chunk
        r[9] = __builtin_nontemporal_load(&row[tid + 2304]);

    // ---- pass 1: max + first-occurrence argmax (4 parallel chains) ----
    float m0 = -INFINITY, m1 = -INFINITY, m2 = -INFINITY, m3 = -INFINITY;
    int   i0 = 0x7fffffff, i1 = 0x7fffffff, i2 = 0x7fffffff, i3 = 0x7fffffff;
#pragma unroll
    for (int k = 0; k < 10; ++k) {
        const int gi = (tid + k * 256) * 4;    // ascending in k per chain
        if (r[k].x > m0) { m0 = r[k].x; i0 = gi + 0; }
        if (r[k].y > m1) { m1 = r[k].y; i1 = gi + 1; }
        if (r[k].z > m2) { m2 = r[k].z; i2 = gi + 2; }
        if (r[k].w > m3) { m3 = r[k].w; i3 = gi + 3; }
    }
    float m = m0;
    int   idx = i0;
    if (m1 > m || (m1 == m && i1 < idx)) { m = m1; idx = i1; }
    if (m2 > m || (m2 == m && i2 < idx)) { m = m2; idx = i2; }
    if (m3 > m || (m3 == m && i3 < idx)) { m = m3; idx = i3; }

    // ---- pass 2: s = sum exp(v - m), in exp2 domain, 4 accumulators ----
    const float mK = m * LOG2E;
    float s0 = 0.0f, s1 = 0.0f, s2 = 0.0f, s3 = 0.0f;
#pragma unroll
    for (int k = 0; k < 10; ++k) {
        s0 += EXP2F(__builtin_fmaf(r[k].x, LOG2E, -mK));
        s1 += EXP2F(__builtin_fmaf(r[k].y, LOG2E, -mK));
        s2 += EXP2F(__builtin_fmaf(r[k].z, LOG2E, -mK));
        s3 += EXP2F(__builtin_fmaf(r[k].w, LOG2E, -mK));
    }
    float s = (s0 + s1) + (s2 + s3);

    // ---- wave-level reduce (64 lanes) ----
#pragma unroll
    for (int off = 32; off > 0; off >>= 1) {
        float mo = __shfl_down(m, off);
        float so = __shfl_down(s, off);
        int   io = __shfl_down(idx, off);
        if (mo > m || (mo == m && io < idx)) {
            s = so + s * EXP2F((m - mo) * LOG2E);
            m = mo; idx = io;
        } else {
            s = s + so * EXP2F((mo - m) * LOG2E);
        }
    }

    // ---- cross-wave reduce (4 waves) ----
    __shared__ float sm[4], ss[4];
    __shared__ int   si[4];
    const int wave = tid >> 6;
    if ((tid & 63) == 0) { sm[wave] = m; ss[wave] = s; si[wave] = idx; }
    __syncthreads();
    if (tid == 0) {
#pragma unroll
        for (int w = 1; w < 4; ++w) {
            float mo = sm[w], so = ss[w];
            int   io = si[w];
            if (mo > m || (mo == m && io < idx)) {
                s = so + s * EXP2F((m - mo) * LOG2E);
                m = mo; idx = io;
            } else {
                s = s + so * EXP2F((mo - m) * LOG2E);
            }
        }
        preds[frame]  = idx;
        mlp[frame]    = -LOG2F(s) * LN2;   // maxlogp = -ln(sum exp(l-m))
        tokens[frame] = 0.0f;              // zero-init output; kernel 2 scatters
    }
}

// ---------------------------------------------------------------------------
// Kernel 2: CTC collapse. One wave per batch row; all 16 chunks prefetched
// into registers, prev via shuffle. Invalid frames (t >= len) carry poisoned
// preds/mlp, but `keep` fails on (t < len) first and a valid frame's prev is
// always a valid frame — garbage never propagates.
// Outputs stored as float32 (harness reads the flat buffer as fp32).
// ---------------------------------------------------------------------------
__global__ __launch_bounds__(64) void collapse_kernel(
    const int*   __restrict__ preds,    // [B*T]
    const float* __restrict__ mlp,      // [B*T]
    const int*   __restrict__ lengths,  // [B]
    float* __restrict__ tokens,         // [B*T] (zeroed by kernel 1)
    float* __restrict__ out_len,        // [B]
    float* __restrict__ scores)         // [B]
{
    const int b    = blockIdx.x;
    const int lane = threadIdx.x;
    const int len  = lengths[b];
    const int*   prow = preds + b * T_;
    const float* srow = mlp   + b * T_;
    float* trow = tokens + b * T_;

    int   p_r[16];
    float s_r[16];
#pragma unroll
    for (int c = 0; c < 16; ++c) {
        p_r[c] = prow[c * 64 + lane];
        s_r[c] = srow[c * 64 + lane];
    }

    int   base  = 0;
    int   carry = BLANK_;
    float acc   = 0.0f;
#pragma unroll
    for (int c = 0; c < 16; ++c) {
        const int t = c * 64 + lane;
        const int p = p_r[c];
        int prev = __shfl_up(p, 1);
        if (lane == 0) prev = carry;
        carry = __shfl(p, 63);
        const bool keep = (t < len) && (p != BLANK_) && (p != prev);
        const unsigned long long mask = __ballot(keep);
        const int pos = base + __popcll(mask & ((1ull << lane) - 1ull));
        if (keep) {
            trow[pos] = (float)p;       // token ids < 10000: exact in fp32
            acc += s_r[c];
        }
        base += __popcll(mask);
    }

#pragma unroll
    for (int off = 32; off > 0; off >>= 1)
        acc += __shfl_down(acc, off);

    if (lane == 0) {
        out_len[b] = (float)base;       // <= 1024: exact in fp32
        scores[b]  = acc;
    }
}

extern "C" void kernel_launch(void* const* d_in, const int* in_sizes, int n_in,
                              void* d_out, int out_size, void* d_ws, size_t ws_size,
                              hipStream_t stream) {
    const float* logits  = (const float*)d_in[0];
    const int*   lengths = (const int*)d_in[1];

    // Output layout (fp32 view): tokens [B*T] | out_len [B] | scores [B]
    float* out_f  = (float*)d_out;
    float* tokens = out_f;
    float* outlen = out_f + B_ * T_;
    float* scores = out_f + B_ * T_ + B_;

    // Workspace: preds [B*T] int32, mlp [B*T] float32 (64 KB total)
    int*   preds = (int*)d_ws;
    float* mlpws = (float*)((char*)d_ws + (size_t)B_ * T_ * sizeof(int));

    frame_reduce_kernel<<<B_ * T_, 256, 0, stream>>>(logits, lengths, preds, mlpws, tokens);
    collapse_kernel<<<B_, 64, 0, stream>>>(preds, mlpws, lengths, tokens, outlen, scores);
}